// Round 9
// baseline (102.672 us; speedup 1.0000x reference)
//
#include <hip/hip_runtime.h>
#include <hip/hip_bf16.h>

typedef unsigned int u32;
typedef unsigned short u16;
typedef _Float16 h2t __attribute__((ext_vector_type(2)));

#define BATCH 2
#define NNODE 768
#define NROWS (BATCH*NNODE)   // 1536
#define CDIM 64
#define ODIM 64
#define EDIM 18
#define E1DIM 32
#define PEDIM 32
#define ADIM 32
#define GDIM 64
#define WCAP 64               // per-wave edge cap (half-row: Bin(384,.05) mu=19.2 sd=4.3)
#define TROW 68               // team row stride in u32: g-stage needs 64; 68 = 16B-aligned pad

// workspace float offsets
#define OFF_SELF  0
#define OFF_NEIGH (OFF_SELF + NROWS*ODIM)
#define OFF_XAI   (OFF_NEIGH + NROWS*ODIM)
#define OFF_XAJ   (OFF_XAI + NROWS*ADIM)
#define OFF_XG    (OFF_XAJ + NROWS*ADIM)
#define OFF_MSG   (OFF_XG + NROWS*GDIM)
#define OFF_PKW   (OFF_MSG + NROWS*ODIM)   // u32 region, 4384 entries

// packed-weight u32 offsets
#define PW_WE1 0        // 9*32  = 288
#define PW_WE2 288      // 16*32 = 512
#define PW_WAE 800      // 16*32 = 512
#define PW_WGE 1312     // 16*64 = 1024
#define PW_WG2 2336     // 32*64 = 2048  (NOT staged to LDS; read from L1)
#define PW_LDS 2336     // u32s staged to LDS
#define PW_TOT 4384

__device__ __forceinline__ float4 ld4s(const float* p) { return *(const float4*)p; }
__device__ __forceinline__ void add4(float4& a, const float4 b) {
  a.x += b.x; a.y += b.y; a.z += b.z; a.w += b.w;
}
__device__ __forceinline__ void relu4(float4& a) {
  a.x = fmaxf(a.x, 0.f); a.y = fmaxf(a.y, 0.f); a.z = fmaxf(a.z, 0.f); a.w = fmaxf(a.w, 0.f);
}
__device__ __forceinline__ float wredsum(float a) {
  a += __shfl_xor(a, 4); a += __shfl_xor(a, 8); a += __shfl_xor(a, 16); a += __shfl_xor(a, 32);
  return a;
}
__device__ __forceinline__ float wredmax(float a) {
  a = fmaxf(a, __shfl_xor(a, 4)); a = fmaxf(a, __shfl_xor(a, 8));
  a = fmaxf(a, __shfl_xor(a, 16)); a = fmaxf(a, __shfl_xor(a, 32));
  return a;
}
__device__ __forceinline__ float sigm(float v) { return 1.f / (1.f + __expf(-v)); }

// f16 pair dot with f32 accumulate (V_DOT2_F32_F16); exact products, f32 accum
__device__ __forceinline__ float fdot2(u32 a, u32 b, float c) {
#if __has_builtin(__builtin_amdgcn_fdot2)
  return __builtin_amdgcn_fdot2(__builtin_bit_cast(h2t, a), __builtin_bit_cast(h2t, b), c, false);
#else
  const h2t av = __builtin_bit_cast(h2t, a), bv = __builtin_bit_cast(h2t, b);
  return c + (float)av.x * (float)bv.x + (float)av.y * (float)bv.y;
#endif
}
__device__ __forceinline__ u32 pk(float a, float b) {
  return __builtin_bit_cast(u32, __builtin_amdgcn_cvt_pkrtz(a, b));
}
#define D4(ACC, W, S) { ACC.x = fdot2(W.x, S, ACC.x); ACC.y = fdot2(W.y, S, ACC.y); \
                        ACC.z = fdot2(W.z, S, ACC.z); ACC.w = fdot2(W.w, S, ACC.w); }

// ---------------- Kernel P: pack weights to f16 k-pairs (once per launch) ----
__global__ __launch_bounds__(256) void pack_weights(
    const float* __restrict__ We1, const float* __restrict__ We2,
    const float* __restrict__ Wa1, const float* __restrict__ Wg1,
    const float* __restrict__ Wg2, u32* __restrict__ pw)
{
  const int i = blockIdx.x*256 + threadIdx.x;
  if (i < 288) {
    const int kp = i >> 5, o = i & 31;
    pw[PW_WE1 + i] = pk(We1[(2*kp)*E1DIM + o], We1[(2*kp+1)*E1DIM + o]);
  } else if (i < 800) {
    const int t = i - 288, kp = t >> 5, o = t & 31;
    pw[i] = pk(We2[(2*kp)*PEDIM + o], We2[(2*kp+1)*PEDIM + o]);
  } else if (i < 1312) {
    const int t = i - 800, kp = t >> 5, o = t & 31;
    const float* b = Wa1 + 2*CDIM*ADIM;
    pw[i] = pk(b[(2*kp)*ADIM + o], b[(2*kp+1)*ADIM + o]);
  } else if (i < 2336) {
    const int t = i - 1312, kp = t >> 6, o = t & 63;
    const float* b = Wg1 + CDIM*GDIM;
    pw[i] = pk(b[(2*kp)*GDIM + o], b[(2*kp+1)*GDIM + o]);
  } else if (i < PW_TOT) {
    const int t = i - 2336, kp = t >> 6, o = t & 63;
    pw[i] = pk(Wg2[(2*kp)*ODIM + o], Wg2[(2*kp+1)*ODIM + o]);
  }
}

// ---------------- Kernel A: per-node linear projections (fp32) ----------------
__global__ __launch_bounds__(64) void node_pre(
    const float* __restrict__ x, const float* __restrict__ Ws, const float* __restrict__ bs,
    const float* __restrict__ Wn, const float* __restrict__ bn,
    const float* __restrict__ Wa1, const float* __restrict__ Wg1,
    float* __restrict__ ws)
{
  const int n = blockIdx.x;
  const int o = threadIdx.x;
  __shared__ float sx[CDIM];
  sx[o] = x[n*CDIM + o];
  __syncthreads();
  float aS = bs[o], aN = bn[o], aG = 0.f;
  #pragma unroll
  for (int t = 0; t < CDIM; ++t) {
    float xt = sx[t];
    aS += xt * Ws[t*ODIM + o];
    aN += xt * Wn[t*ODIM + o];
    aG += xt * Wg1[t*GDIM + o];
  }
  ws[OFF_SELF  + n*ODIM + o] = aS;
  ws[OFF_NEIGH + n*ODIM + o] = aN;
  ws[OFF_XG    + n*GDIM + o] = aG;
  if (o < ADIM) {
    float aI = 0.f, aJ = 0.f;
    #pragma unroll
    for (int t = 0; t < CDIM; ++t) {
      float xt = sx[t];
      aI += xt * Wa1[t*ADIM + o];
      aJ += xt * Wa1[(CDIM + t)*ADIM + o];
    }
    ws[OFF_XAI + n*ADIM + o] = aI;
    ws[OFF_XAJ + n*ADIM + o] = aJ;
  }
}

// ---------------- Kernel B: sparse per-edge MLP + online softmax ----------------
// ONE row per block, 2 waves; wave w owns adjacency columns [384w, 384w+384).
// 4-lane teams, 2 edges/team = 32 edge slots per wave iteration.
// Weights pre-packed f16 (kernel P): small ones staged to LDS, Wg2 read from
// global (L1-resident broadcast). Target <=128 VGPR for 4 waves/SIMD.
__global__ __launch_bounds__(128, 4) void edge_rows(
    const float* __restrict__ adj, const float* __restrict__ ef,
    const float* __restrict__ be1, const float* __restrict__ be2,
    const float* __restrict__ ba1, const float* __restrict__ Wa2,
    const float* __restrict__ ba2, const float* __restrict__ bg1,
    const float* __restrict__ bg2,
    const u32* __restrict__ pw, float* __restrict__ ws)
{
  __shared__ __align__(16) u32 sW[PW_LDS];         // 9344 B
  __shared__ __align__(16) float sWa2[ADIM];
  __shared__ __align__(16) float sbe1[E1DIM];
  __shared__ __align__(16) float sbe2[PEDIM];
  __shared__ __align__(16) float sba1[ADIM];
  __shared__ __align__(16) float sbg1[GDIM];
  __shared__ __align__(16) float sbg2[GDIM];
  __shared__ __align__(16) u32 tbuf[2][16][TROW];  // 8704 B
  __shared__ __align__(16) float smerge[2][80];    // 640 B
  __shared__ u16 slist[2][WCAP];                   // 256 B

  const int tid = threadIdx.x;
  const int wv = tid >> 6, lane = tid & 63;
  const int row = blockIdx.x;
  const int jbase = (row >= NNODE) ? NNODE : 0;   // batch offset for node tables
  const int e = lane >> 2;        // edge slot (team)
  const int p = lane & 3;         // channel part

  // ---- stage packed weights: straight uint4 copy (584 uint4) ----
  for (int i = tid; i < PW_LDS/4; i += 128)
    ((uint4*)sW)[i] = ((const uint4*)pw)[i];
  if (tid < 32) { sWa2[tid] = Wa2[tid]; sbe1[tid] = be1[tid]; sbe2[tid] = be2[tid]; sba1[tid] = ba1[tid]; }
  if (tid >= 64 && tid < 128) { sbg1[tid-64] = bg1[tid-64]; sbg2[tid-64] = bg2[tid-64]; }

  // per-lane row constants
  const float4 xai0 = ld4s(ws + OFF_XAI + (size_t)row*ADIM + 8*p);
  const float4 xai1 = ld4s(ws + OFF_XAI + (size_t)row*ADIM + 8*p + 4);

  // ---- per-wave neighbor compaction over this wave's half of the columns ----
  int cnt = 0;
  const float* arow = adj + (size_t)row * NNODE + 384*wv;
  const unsigned long long lt = (lane == 0) ? 0ull : ((~0ull) >> (64 - lane));
  for (int jb = 0; jb < 384; jb += 64) {
    const int j = jb + lane;
    const bool act = arow[j] > 0.f;
    const unsigned long long mask = __ballot(act);
    if (act) {
      const int idx = cnt + __popcll(mask & lt);
      if (idx < WCAP) slist[wv][idx] = (u16)(384*wv + j);
    }
    cnt += __popcll(mask);
  }
  const int degw = (cnt < WCAP) ? cnt : WCAP;
  __syncthreads();   // staged weights + lists visible

  const float ba2v = ba2[0];
  const float* __restrict__ wxaj = ws + OFF_XAJ;
  const float* __restrict__ wxg  = ws + OFF_XG;
  const float* __restrict__ wnei = ws + OFF_NEIGH;
  const u32* __restrict__ pwWg2 = pw + PW_WG2;
  const u16* sl_ = slist[wv];
  const float* efbase = ef + (size_t)row * NNODE * EDIM;

  u32* tb_ = &tbuf[wv][e][0];   // team row (4 lanes share)

  float m = -INFINITY, s = 0.f;
  float4 acc0 = {0,0,0,0}, acc1 = {0,0,0,0}, acc2 = {0,0,0,0}, acc3 = {0,0,0,0};

  const int nbw = (degw + 31) >> 5;
  for (int kb = 0; kb < nbw; ++kb) {
    const int kA = kb*32 + e, kB = kA + 16;
    const bool vA = kA < degw;
    const bool vB = kB < degw;
    const int jA = sl_[vA ? kA : 0];
    const int jB = sl_[vB ? kB : 0];
    const int jgA = jbase + jA, jgB = jbase + jB;

    // ---- edge features -> packed f16 pairs ----
    const float2* pA = (const float2*)(efbase + (size_t)jA * EDIM);
    const float2* pB = (const float2*)(efbase + (size_t)jB * EDIM);
    const float2 qa0=pA[0],qa1=pA[1],qa2=pA[2],qa3=pA[3],qa4=pA[4],
                 qa5=pA[5],qa6=pA[6],qa7=pA[7],qa8=pA[8];
    const float2 qb0=pB[0],qb1=pB[1],qb2=pB[2],qb3=pB[3],qb4=pB[4],
                 qb5=pB[5],qb6=pB[6],qb7=pB[7],qb8=pB[8];
    const u32 fA0=pk(qa0.x,qa0.y), fA1=pk(qa1.x,qa1.y), fA2=pk(qa2.x,qa2.y),
              fA3=pk(qa3.x,qa3.y), fA4=pk(qa4.x,qa4.y), fA5=pk(qa5.x,qa5.y),
              fA6=pk(qa6.x,qa6.y), fA7=pk(qa7.x,qa7.y), fA8=pk(qa8.x,qa8.y);
    const u32 fB0=pk(qb0.x,qb0.y), fB1=pk(qb1.x,qb1.y), fB2=pk(qb2.x,qb2.y),
              fB3=pk(qb3.x,qb3.y), fB4=pk(qb4.x,qb4.y), fB5=pk(qb5.x,qb5.y),
              fB6=pk(qb6.x,qb6.y), fB7=pk(qb7.x,qb7.y), fB8=pk(qb8.x,qb8.y);

    // ---- e1 = relu(ef @ We1 + be1): 8 ch/lane, 9 k-pairs ----
    float4 eAa = ld4s(&sbe1[8*p]), eAb = ld4s(&sbe1[8*p+4]);
    float4 eBa = eAa, eBb = eAb;
    #define E1S(KP, AA, BB) { \
      const uint4 w0 = *(const uint4*)&sW[PW_WE1 + (KP)*E1DIM + 8*p]; \
      const uint4 w1 = *(const uint4*)&sW[PW_WE1 + (KP)*E1DIM + 8*p + 4]; \
      D4(eAa, w0, AA) D4(eAb, w1, AA) D4(eBa, w0, BB) D4(eBb, w1, BB) }
    E1S(0,fA0,fB0) E1S(1,fA1,fB1) E1S(2,fA2,fB2) E1S(3,fA3,fB3) E1S(4,fA4,fB4)
    E1S(5,fA5,fB5) E1S(6,fA6,fB6) E1S(7,fA7,fB7) E1S(8,fA8,fB8)
    #undef E1S
    relu4(eAa); relu4(eAb); relu4(eBa); relu4(eBb);
    {
      uint2 t0; t0.x = pk(eAa.x,eAa.y); t0.y = pk(eBa.x,eBa.y);
      uint2 t1; t1.x = pk(eAa.z,eAa.w); t1.y = pk(eBa.z,eBa.w);
      uint2 t2; t2.x = pk(eAb.x,eAb.y); t2.y = pk(eBb.x,eBb.y);
      uint2 t3; t3.x = pk(eAb.z,eAb.w); t3.y = pk(eBb.z,eBb.w);
      *(uint2*)&tb_[8*p+0] = t0; *(uint2*)&tb_[8*p+2] = t1;
      *(uint2*)&tb_[8*p+4] = t2; *(uint2*)&tb_[8*p+6] = t3;
    }
    // wave-lockstep + in-order DS pipe: team reads below see all 4 lanes' writes

    // ---- pe = relu(e1 @ We2 + be2) ----
    float4 pAa = ld4s(&sbe2[8*p]), pAb = ld4s(&sbe2[8*p+4]);
    float4 pBa = pAa, pBb = pAb;
    #pragma unroll 4
    for (int kp = 0; kp < 16; ++kp) {
      const uint2 ab = *(const uint2*)&tb_[2*kp];
      const uint4 w0 = *(const uint4*)&sW[PW_WE2 + kp*PEDIM + 8*p];
      const uint4 w1 = *(const uint4*)&sW[PW_WE2 + kp*PEDIM + 8*p + 4];
      D4(pAa, w0, ab.x) D4(pAb, w1, ab.x) D4(pBa, w0, ab.y) D4(pBb, w1, ab.y)
    }
    relu4(pAa); relu4(pAb); relu4(pBa); relu4(pBb);
    {
      uint2 t0; t0.x = pk(pAa.x,pAa.y); t0.y = pk(pBa.x,pBa.y);
      uint2 t1; t1.x = pk(pAa.z,pAa.w); t1.y = pk(pBa.z,pBa.w);
      uint2 t2; t2.x = pk(pAb.x,pAb.y); t2.y = pk(pBb.x,pBb.y);
      uint2 t3; t3.x = pk(pAb.z,pAb.w); t3.y = pk(pBb.z,pBb.w);
      *(uint2*)&tb_[8*p+0] = t0; *(uint2*)&tb_[8*p+2] = t1;
      *(uint2*)&tb_[8*p+4] = t2; *(uint2*)&tb_[8*p+6] = t3;
    }

    // ---- h (8 ch/lane) and g (16 ch/lane) from the pe broadcast ----
    float4 hAa = ld4s(&sba1[8*p]), hAb = ld4s(&sba1[8*p+4]);
    float4 hBa = hAa, hBb = hAb;
    float4 gA0 = ld4s(&sbg1[16*p]),   gA1 = ld4s(&sbg1[16*p+4]),
           gA2 = ld4s(&sbg1[16*p+8]), gA3 = ld4s(&sbg1[16*p+12]);
    float4 gB0 = gA0, gB1 = gA1, gB2 = gA2, gB3 = gA3;
    #pragma unroll 4
    for (int kp = 0; kp < 16; ++kp) {
      const uint2 ab = *(const uint2*)&tb_[2*kp];
      const uint4 wh0 = *(const uint4*)&sW[PW_WAE + kp*ADIM + 8*p];
      const uint4 wh1 = *(const uint4*)&sW[PW_WAE + kp*ADIM + 8*p + 4];
      D4(hAa, wh0, ab.x) D4(hAb, wh1, ab.x) D4(hBa, wh0, ab.y) D4(hBb, wh1, ab.y)
      const uint4 wg0 = *(const uint4*)&sW[PW_WGE + kp*GDIM + 16*p];
      const uint4 wg1 = *(const uint4*)&sW[PW_WGE + kp*GDIM + 16*p + 4];
      const uint4 wg2 = *(const uint4*)&sW[PW_WGE + kp*GDIM + 16*p + 8];
      const uint4 wg3 = *(const uint4*)&sW[PW_WGE + kp*GDIM + 16*p + 12];
      D4(gA0, wg0, ab.x) D4(gA1, wg1, ab.x) D4(gA2, wg2, ab.x) D4(gA3, wg3, ab.x)
      D4(gB0, wg0, ab.y) D4(gB1, wg1, ab.y) D4(gB2, wg2, ab.y) D4(gB3, wg3, ab.y)
    }
    // node-table adds (fp32)
    {
      const float* xjpA = wxaj + (size_t)jgA*ADIM + 8*p;
      const float* xjpB = wxaj + (size_t)jgB*ADIM + 8*p;
      add4(hAa, ld4s(xjpA)); add4(hAb, ld4s(xjpA + 4));
      add4(hBa, ld4s(xjpB)); add4(hBb, ld4s(xjpB + 4));
      add4(hAa, xai0); add4(hAb, xai1); add4(hBa, xai0); add4(hBb, xai1);
      const float* xgpA = wxg + (size_t)jgA*GDIM + 16*p;
      const float* xgpB = wxg + (size_t)jgB*GDIM + 16*p;
      add4(gA0, ld4s(xgpA)); add4(gA1, ld4s(xgpA+4)); add4(gA2, ld4s(xgpA+8)); add4(gA3, ld4s(xgpA+12));
      add4(gB0, ld4s(xgpB)); add4(gB1, ld4s(xgpB+4)); add4(gB2, ld4s(xgpB+8)); add4(gB3, ld4s(xgpB+12));
    }

    // ---- logits: team-reduce relu(h) @ Wa2 (fp32) ----
    const float4 wa20 = ld4s(&sWa2[8*p]), wa21 = ld4s(&sWa2[8*p+4]);
    float lpA = fmaxf(hAa.x,0.f)*wa20.x + fmaxf(hAa.y,0.f)*wa20.y
              + fmaxf(hAa.z,0.f)*wa20.z + fmaxf(hAa.w,0.f)*wa20.w
              + fmaxf(hAb.x,0.f)*wa21.x + fmaxf(hAb.y,0.f)*wa21.y
              + fmaxf(hAb.z,0.f)*wa21.z + fmaxf(hAb.w,0.f)*wa21.w;
    float lpB = fmaxf(hBa.x,0.f)*wa20.x + fmaxf(hBa.y,0.f)*wa20.y
              + fmaxf(hBa.z,0.f)*wa20.z + fmaxf(hBa.w,0.f)*wa20.w
              + fmaxf(hBb.x,0.f)*wa21.x + fmaxf(hBb.y,0.f)*wa21.y
              + fmaxf(hBb.z,0.f)*wa21.z + fmaxf(hBb.w,0.f)*wa21.w;
    lpA += __shfl_xor(lpA, 1); lpA += __shfl_xor(lpA, 2);
    lpB += __shfl_xor(lpB, 1); lpB += __shfl_xor(lpB, 2);
    const float lA = vA ? (lpA + ba2v) : -INFINITY;
    const float lB = vB ? (lpB + ba2v) : -INFINITY;

    // ---- online softmax over both edges ----
    const float mn1 = fmaxf(m, lA);
    const float al1 = (m  > -INFINITY) ? __expf(m  - mn1) : 0.f;
    const float w1  = (lA > -INFINITY) ? __expf(lA - mn1) : 0.f;
    const float s1  = s*al1 + w1;
    const float mn2 = fmaxf(mn1, lB);
    const float al2 = (mn1 > -INFINITY) ? __expf(mn1 - mn2) : 0.f;
    const float w2  = (lB  > -INFINITY) ? __expf(lB  - mn2) : 0.f;
    s = s1*al2 + w2;  m = mn2;
    const float aall = al1*al2, cA = w1*al2, cB = w2;

    // ---- stage relu(g) as f16 pairs (64 u32/team; TROW=68 accommodates) ----
    relu4(gA0); relu4(gA1); relu4(gA2); relu4(gA3);
    relu4(gB0); relu4(gB1); relu4(gB2); relu4(gB3);
    {
      uint2 t;
      t.x = pk(gA0.x,gA0.y); t.y = pk(gB0.x,gB0.y); *(uint2*)&tb_[16*p+0]  = t;
      t.x = pk(gA0.z,gA0.w); t.y = pk(gB0.z,gB0.w); *(uint2*)&tb_[16*p+2]  = t;
      t.x = pk(gA1.x,gA1.y); t.y = pk(gB1.x,gB1.y); *(uint2*)&tb_[16*p+4]  = t;
      t.x = pk(gA1.z,gA1.w); t.y = pk(gB1.z,gB1.w); *(uint2*)&tb_[16*p+6]  = t;
      t.x = pk(gA2.x,gA2.y); t.y = pk(gB2.x,gB2.y); *(uint2*)&tb_[16*p+8]  = t;
      t.x = pk(gA2.z,gA2.w); t.y = pk(gB2.z,gB2.w); *(uint2*)&tb_[16*p+10] = t;
      t.x = pk(gA3.x,gA3.y); t.y = pk(gB3.x,gB3.y); *(uint2*)&tb_[16*p+12] = t;
      t.x = pk(gA3.z,gA3.w); t.y = pk(gB3.z,gB3.w); *(uint2*)&tb_[16*p+14] = t;
    }

    // ---- gates matvec (64x64); Wg2 read from global (L1-hot broadcast) ----
    float4 aA0 = ld4s(&sbg2[16*p]),   aA1 = ld4s(&sbg2[16*p+4]),
           aA2 = ld4s(&sbg2[16*p+8]), aA3 = ld4s(&sbg2[16*p+12]);
    float4 aB0 = aA0, aB1 = aA1, aB2 = aA2, aB3 = aA3;
    #pragma unroll 4
    for (int kp = 0; kp < 32; ++kp) {
      const uint2 gg = *(const uint2*)&tb_[2*kp];
      const uint4 w0 = *(const uint4*)&pwWg2[kp*ODIM + 16*p];
      const uint4 w1 = *(const uint4*)&pwWg2[kp*ODIM + 16*p + 4];
      const uint4 w2 = *(const uint4*)&pwWg2[kp*ODIM + 16*p + 8];
      const uint4 w3 = *(const uint4*)&pwWg2[kp*ODIM + 16*p + 12];
      D4(aA0, w0, gg.x) D4(aA1, w1, gg.x) D4(aA2, w2, gg.x) D4(aA3, w3, gg.x)
      D4(aB0, w0, gg.y) D4(aB1, w1, gg.y) D4(aB2, w2, gg.y) D4(aB3, w3, gg.y)
    }

    // ---- acc = acc*aall + cA*sigmoid(gaA)*nei[jA] + cB*sigmoid(gaB)*nei[jB] ----
    const float* njpA = wnei + (size_t)jgA*ODIM + 16*p;
    const float* njpB = wnei + (size_t)jgB*ODIM + 16*p;
    const float4 nA0 = ld4s(njpA), nA1 = ld4s(njpA+4), nA2 = ld4s(njpA+8), nA3 = ld4s(njpA+12);
    const float4 nB0 = ld4s(njpB), nB1 = ld4s(njpB+4), nB2 = ld4s(njpB+8), nB3 = ld4s(njpB+12);
    #define ACCU(AC, GA, NA, GB, NB) \
      AC.x = AC.x*aall + cA*sigm((GA).x)*(NA).x + cB*sigm((GB).x)*(NB).x; \
      AC.y = AC.y*aall + cA*sigm((GA).y)*(NA).y + cB*sigm((GB).y)*(NB).y; \
      AC.z = AC.z*aall + cA*sigm((GA).z)*(NA).z + cB*sigm((GB).z)*(NB).z; \
      AC.w = AC.w*aall + cA*sigm((GA).w)*(NA).w + cB*sigm((GB).w)*(NB).w;
    ACCU(acc0, aA0, nA0, aB0, nB0)
    ACCU(acc1, aA1, nA1, aB1, nB1)
    ACCU(acc2, aA2, nA2, aB2, nB2)
    ACCU(acc3, aA3, nA3, aB3, nB3)
    #undef ACCU
  }

  // ---- per-wave merge across the 16 edge slots ----
  const float mw = wredmax(m);
  const float alphaF = (s > 0.f) ? __expf(m - mw) : 0.f;
  const float sl = wredsum(s * alphaF);
  acc0.x = wredsum(acc0.x * alphaF); acc0.y = wredsum(acc0.y * alphaF);
  acc0.z = wredsum(acc0.z * alphaF); acc0.w = wredsum(acc0.w * alphaF);
  acc1.x = wredsum(acc1.x * alphaF); acc1.y = wredsum(acc1.y * alphaF);
  acc1.z = wredsum(acc1.z * alphaF); acc1.w = wredsum(acc1.w * alphaF);
  acc2.x = wredsum(acc2.x * alphaF); acc2.y = wredsum(acc2.y * alphaF);
  acc2.z = wredsum(acc2.z * alphaF); acc2.w = wredsum(acc2.w * alphaF);
  acc3.x = wredsum(acc3.x * alphaF); acc3.y = wredsum(acc3.y * alphaF);
  acc3.z = wredsum(acc3.z * alphaF); acc3.w = wredsum(acc3.w * alphaF);
  if (e == 0) {
    if (p == 0) { smerge[wv][0] = mw; smerge[wv][1] = sl; }
    *(float4*)&smerge[wv][8 + 16*p + 0]  = acc0;
    *(float4*)&smerge[wv][8 + 16*p + 4]  = acc1;
    *(float4*)&smerge[wv][8 + 16*p + 8]  = acc2;
    *(float4*)&smerge[wv][8 + 16*p + 12] = acc3;
  }
  __syncthreads();

  // ---- cross-wave merge + write msg (wave 0) ----
  if (tid < ODIM) {
    const float mw0 = smerge[0][0], sl0 = smerge[0][1];
    const float mw1 = smerge[1][0], sl1 = smerge[1][1];
    const float MW = fmaxf(mw0, mw1);
    const float b0 = (sl0 > 0.f) ? __expf(mw0 - MW) : 0.f;
    const float b1 = (sl1 > 0.f) ? __expf(mw1 - MW) : 0.f;
    const float denom = sl0*b0 + sl1*b1;
    const float rs = 1.f / fmaxf(denom, 1e-30f);
    ws[OFF_MSG + (size_t)row*ODIM + tid] =
        (smerge[0][8+tid]*b0 + smerge[1][8+tid]*b1) * rs;
  }
}

// ---------------- Kernel C: output MLP (fp32) ----------------
__global__ __launch_bounds__(64) void final_out(
    const float* __restrict__ ws, const float* __restrict__ Wc1, const float* __restrict__ bc1,
    const float* __restrict__ Wc2, const float* __restrict__ bc2, float* __restrict__ out)
{
  const int n = blockIdx.x, o = threadIdx.x;
  __shared__ float comb[2*ODIM];
  __shared__ float h1[ODIM];
  comb[o] = ws[OFF_SELF + n*ODIM + o];
  comb[ODIM + o] = ws[OFF_MSG + n*ODIM + o];
  __syncthreads();
  float a = bc1[o];
  #pragma unroll
  for (int t = 0; t < 2*ODIM; ++t) a += comb[t] * Wc1[t*ODIM + o];
  h1[o] = fmaxf(a, 0.f);
  __syncthreads();
  float b = bc2[o];
  #pragma unroll
  for (int t = 0; t < ODIM; ++t) b += h1[t] * Wc2[t*ODIM + o];
  out[n*ODIM + o] = b;
}

extern "C" void kernel_launch(void* const* d_in, const int* in_sizes, int n_in,
                              void* d_out, int out_size, void* d_ws, size_t ws_size,
                              hipStream_t stream)
{
  const float* x   = (const float*)d_in[0];
  const float* adj = (const float*)d_in[1];
  const float* ef  = (const float*)d_in[2];
  const float* Ws  = (const float*)d_in[3];
  const float* bs  = (const float*)d_in[4];
  const float* Wn  = (const float*)d_in[5];
  const float* bn  = (const float*)d_in[6];
  const float* We1 = (const float*)d_in[7];
  const float* be1 = (const float*)d_in[8];
  const float* We2 = (const float*)d_in[9];
  const float* be2 = (const float*)d_in[10];
  const float* Wa1 = (const float*)d_in[11];
  const float* ba1 = (const float*)d_in[12];
  const float* Wa2 = (const float*)d_in[13];
  const float* ba2 = (const float*)d_in[14];
  const float* Wg1 = (const float*)d_in[15];
  const float* bg1 = (const float*)d_in[16];
  const float* Wg2 = (const float*)d_in[17];
  const float* bg2 = (const float*)d_in[18];
  const float* Wc1 = (const float*)d_in[19];
  const float* bc1 = (const float*)d_in[20];
  const float* Wc2 = (const float*)d_in[21];
  const float* bc2 = (const float*)d_in[22];
  float* ws  = (float*)d_ws;
  u32* pw = (u32*)(ws + OFF_PKW);
  float* out = (float*)d_out;

  pack_weights<<<(PW_TOT + 255)/256, 256, 0, stream>>>(We1, We2, Wa1, Wg1, Wg2, pw);
  node_pre<<<NROWS, 64, 0, stream>>>(x, Ws, bs, Wn, bn, Wa1, Wg1, ws);
  edge_rows<<<NROWS, 128, 0, stream>>>(adj, ef, be1, be2, ba1, Wa2, ba2, bg1, bg2,
                                       pw, ws);
  final_out<<<NROWS, 64, 0, stream>>>(ws, Wc1, bc1, Wc2, bc2, out);
}

// Round 10
// 87.373 us; speedup vs baseline: 1.1751x; 1.1751x over previous
//
#include <hip/hip_runtime.h>
#include <hip/hip_bf16.h>

typedef unsigned int u32;
typedef unsigned short u16;
typedef _Float16 h2t __attribute__((ext_vector_type(2)));

#define BATCH 2
#define NNODE 768
#define NROWS (BATCH*NNODE)   // 1536
#define CDIM 64
#define ODIM 64
#define EDIM 18
#define E1DIM 32
#define PEDIM 32
#define ADIM 32
#define GDIM 64
#define WCAP 64               // per-wave edge cap (half-row: Bin(384,.05) mu=19.2 sd=4.3)
#define TROW 68               // team row stride in u32: g-stage needs 64; 68 = 16B-aligned pad

// workspace float offsets
#define OFF_SELF  0
#define OFF_NEIGH (OFF_SELF + NROWS*ODIM)
#define OFF_XAI   (OFF_NEIGH + NROWS*ODIM)
#define OFF_XAJ   (OFF_XAI + NROWS*ADIM)
#define OFF_XG    (OFF_XAJ + NROWS*ADIM)
#define OFF_MSG   (OFF_XG + NROWS*GDIM)
#define OFF_PKW   (OFF_MSG + NROWS*ODIM)   // u32 region, 4384 entries

// packed-weight u32 offsets
#define PW_WE1 0        // 9*32  = 288
#define PW_WE2 288      // 16*32 = 512
#define PW_WAE 800      // 16*32 = 512
#define PW_WGE 1312     // 16*64 = 1024
#define PW_WG2 2336     // 32*64 = 2048  (NOT staged to LDS; read from L1)
#define PW_LDS 2336     // u32s staged to LDS
#define PW_TOT 4384

__device__ __forceinline__ float4 ld4s(const float* p) { return *(const float4*)p; }
__device__ __forceinline__ void add4(float4& a, const float4 b) {
  a.x += b.x; a.y += b.y; a.z += b.z; a.w += b.w;
}
__device__ __forceinline__ void relu4(float4& a) {
  a.x = fmaxf(a.x, 0.f); a.y = fmaxf(a.y, 0.f); a.z = fmaxf(a.z, 0.f); a.w = fmaxf(a.w, 0.f);
}
__device__ __forceinline__ float wredsum(float a) {
  a += __shfl_xor(a, 4); a += __shfl_xor(a, 8); a += __shfl_xor(a, 16); a += __shfl_xor(a, 32);
  return a;
}
__device__ __forceinline__ float wredmax(float a) {
  a = fmaxf(a, __shfl_xor(a, 4)); a = fmaxf(a, __shfl_xor(a, 8));
  a = fmaxf(a, __shfl_xor(a, 16)); a = fmaxf(a, __shfl_xor(a, 32));
  return a;
}
__device__ __forceinline__ float sigm(float v) { return 1.f / (1.f + __expf(-v)); }

// f16 pair dot with f32 accumulate (V_DOT2_F32_F16); exact products, f32 accum
__device__ __forceinline__ float fdot2(u32 a, u32 b, float c) {
#if __has_builtin(__builtin_amdgcn_fdot2)
  return __builtin_amdgcn_fdot2(__builtin_bit_cast(h2t, a), __builtin_bit_cast(h2t, b), c, false);
#else
  const h2t av = __builtin_bit_cast(h2t, a), bv = __builtin_bit_cast(h2t, b);
  return c + (float)av.x * (float)bv.x + (float)av.y * (float)bv.y;
#endif
}
__device__ __forceinline__ u32 pk(float a, float b) {
  return __builtin_bit_cast(u32, __builtin_amdgcn_cvt_pkrtz(a, b));
}
#define D4(ACC, W, S) { ACC.x = fdot2(W.x, S, ACC.x); ACC.y = fdot2(W.y, S, ACC.y); \
                        ACC.z = fdot2(W.z, S, ACC.z); ACC.w = fdot2(W.w, S, ACC.w); }

// ---------------- Kernel P: pack weights to f16 k-pairs (once per launch) ----
__global__ __launch_bounds__(256) void pack_weights(
    const float* __restrict__ We1, const float* __restrict__ We2,
    const float* __restrict__ Wa1, const float* __restrict__ Wg1,
    const float* __restrict__ Wg2, u32* __restrict__ pw)
{
  const int i = blockIdx.x*256 + threadIdx.x;
  if (i < 288) {
    const int kp = i >> 5, o = i & 31;
    pw[PW_WE1 + i] = pk(We1[(2*kp)*E1DIM + o], We1[(2*kp+1)*E1DIM + o]);
  } else if (i < 800) {
    const int t = i - 288, kp = t >> 5, o = t & 31;
    pw[i] = pk(We2[(2*kp)*PEDIM + o], We2[(2*kp+1)*PEDIM + o]);
  } else if (i < 1312) {
    const int t = i - 800, kp = t >> 5, o = t & 31;
    const float* b = Wa1 + 2*CDIM*ADIM;
    pw[i] = pk(b[(2*kp)*ADIM + o], b[(2*kp+1)*ADIM + o]);
  } else if (i < 2336) {
    const int t = i - 1312, kp = t >> 6, o = t & 63;
    const float* b = Wg1 + CDIM*GDIM;
    pw[i] = pk(b[(2*kp)*GDIM + o], b[(2*kp+1)*GDIM + o]);
  } else if (i < PW_TOT) {
    const int t = i - 2336, kp = t >> 6, o = t & 63;
    pw[i] = pk(Wg2[(2*kp)*ODIM + o], Wg2[(2*kp+1)*ODIM + o]);
  }
}

// ---------------- Kernel A: per-node linear projections (fp32) ----------------
__global__ __launch_bounds__(64) void node_pre(
    const float* __restrict__ x, const float* __restrict__ Ws, const float* __restrict__ bs,
    const float* __restrict__ Wn, const float* __restrict__ bn,
    const float* __restrict__ Wa1, const float* __restrict__ Wg1,
    float* __restrict__ ws)
{
  const int n = blockIdx.x;
  const int o = threadIdx.x;
  __shared__ float sx[CDIM];
  sx[o] = x[n*CDIM + o];
  __syncthreads();
  float aS = bs[o], aN = bn[o], aG = 0.f;
  #pragma unroll
  for (int t = 0; t < CDIM; ++t) {
    float xt = sx[t];
    aS += xt * Ws[t*ODIM + o];
    aN += xt * Wn[t*ODIM + o];
    aG += xt * Wg1[t*GDIM + o];
  }
  ws[OFF_SELF  + n*ODIM + o] = aS;
  ws[OFF_NEIGH + n*ODIM + o] = aN;
  ws[OFF_XG    + n*GDIM + o] = aG;
  if (o < ADIM) {
    float aI = 0.f, aJ = 0.f;
    #pragma unroll
    for (int t = 0; t < CDIM; ++t) {
      float xt = sx[t];
      aI += xt * Wa1[t*ADIM + o];
      aJ += xt * Wa1[(CDIM + t)*ADIM + o];
    }
    ws[OFF_XAI + n*ADIM + o] = aI;
    ws[OFF_XAJ + n*ADIM + o] = aJ;
  }
}

// ---------------- Kernel B: sparse per-edge MLP + online softmax ----------------
// ONE row per block, 2 waves; wave w owns adjacency columns [384w, 384w+384).
// 4-lane teams, 2 edges/team = 32 edge slots per wave iteration.
// Weights pre-packed f16 (kernel P): small ones staged to LDS, Wg2 read from
// global (L1-resident broadcast). launch_bounds(128,1): allocator free (~130-190
// VGPR) -- any tighter bound causes catastrophic scratch spills (r5, r9).
__global__ __launch_bounds__(128, 1) void edge_rows(
    const float* __restrict__ adj, const float* __restrict__ ef,
    const float* __restrict__ be1, const float* __restrict__ be2,
    const float* __restrict__ ba1, const float* __restrict__ Wa2,
    const float* __restrict__ ba2, const float* __restrict__ bg1,
    const float* __restrict__ bg2,
    const u32* __restrict__ pw, float* __restrict__ ws)
{
  __shared__ __align__(16) u32 sW[PW_LDS];         // 9344 B
  __shared__ __align__(16) float sWa2[ADIM];
  __shared__ __align__(16) float sbe1[E1DIM];
  __shared__ __align__(16) float sbe2[PEDIM];
  __shared__ __align__(16) float sba1[ADIM];
  __shared__ __align__(16) float sbg1[GDIM];
  __shared__ __align__(16) float sbg2[GDIM];
  __shared__ __align__(16) u32 tbuf[2][16][TROW];  // 8704 B
  __shared__ __align__(16) float smerge[2][80];    // 640 B
  __shared__ u16 slist[2][WCAP];                   // 256 B

  const int tid = threadIdx.x;
  const int wv = tid >> 6, lane = tid & 63;
  const int row = blockIdx.x;
  const int jbase = (row >= NNODE) ? NNODE : 0;   // batch offset for node tables
  const int e = lane >> 2;        // edge slot (team)
  const int p = lane & 3;         // channel part

  // ---- stage packed weights: straight uint4 copy (584 uint4) ----
  for (int i = tid; i < PW_LDS/4; i += 128)
    ((uint4*)sW)[i] = ((const uint4*)pw)[i];
  if (tid < 32) { sWa2[tid] = Wa2[tid]; sbe1[tid] = be1[tid]; sbe2[tid] = be2[tid]; sba1[tid] = ba1[tid]; }
  if (tid >= 64 && tid < 128) { sbg1[tid-64] = bg1[tid-64]; sbg2[tid-64] = bg2[tid-64]; }

  // per-lane row constants
  const float4 xai0 = ld4s(ws + OFF_XAI + (size_t)row*ADIM + 8*p);
  const float4 xai1 = ld4s(ws + OFF_XAI + (size_t)row*ADIM + 8*p + 4);

  // ---- per-wave neighbor compaction over this wave's half of the columns ----
  int cnt = 0;
  const float* arow = adj + (size_t)row * NNODE + 384*wv;
  const unsigned long long lt = (lane == 0) ? 0ull : ((~0ull) >> (64 - lane));
  for (int jb = 0; jb < 384; jb += 64) {
    const int j = jb + lane;
    const bool act = arow[j] > 0.f;
    const unsigned long long mask = __ballot(act);
    if (act) {
      const int idx = cnt + __popcll(mask & lt);
      if (idx < WCAP) slist[wv][idx] = (u16)(384*wv + j);
    }
    cnt += __popcll(mask);
  }
  const int degw = (cnt < WCAP) ? cnt : WCAP;
  __syncthreads();   // staged weights + lists visible

  const float ba2v = ba2[0];
  const float* __restrict__ wxaj = ws + OFF_XAJ;
  const float* __restrict__ wxg  = ws + OFF_XG;
  const float* __restrict__ wnei = ws + OFF_NEIGH;
  const u32* __restrict__ pwWg2 = pw + PW_WG2;
  const u16* sl_ = slist[wv];
  const float* efbase = ef + (size_t)row * NNODE * EDIM;

  u32* tb_ = &tbuf[wv][e][0];   // team row (4 lanes share)

  float m = -INFINITY, s = 0.f;
  float4 acc0 = {0,0,0,0}, acc1 = {0,0,0,0}, acc2 = {0,0,0,0}, acc3 = {0,0,0,0};

  const int nbw = (degw + 31) >> 5;
  for (int kb = 0; kb < nbw; ++kb) {
    const int kA = kb*32 + e, kB = kA + 16;
    const bool vA = kA < degw;
    const bool vB = kB < degw;
    const int jA = sl_[vA ? kA : 0];
    const int jB = sl_[vB ? kB : 0];
    const int jgA = jbase + jA, jgB = jbase + jB;

    // ---- edge features -> packed f16 pairs ----
    const float2* pA = (const float2*)(efbase + (size_t)jA * EDIM);
    const float2* pB = (const float2*)(efbase + (size_t)jB * EDIM);
    const float2 qa0=pA[0],qa1=pA[1],qa2=pA[2],qa3=pA[3],qa4=pA[4],
                 qa5=pA[5],qa6=pA[6],qa7=pA[7],qa8=pA[8];
    const float2 qb0=pB[0],qb1=pB[1],qb2=pB[2],qb3=pB[3],qb4=pB[4],
                 qb5=pB[5],qb6=pB[6],qb7=pB[7],qb8=pB[8];
    const u32 fA0=pk(qa0.x,qa0.y), fA1=pk(qa1.x,qa1.y), fA2=pk(qa2.x,qa2.y),
              fA3=pk(qa3.x,qa3.y), fA4=pk(qa4.x,qa4.y), fA5=pk(qa5.x,qa5.y),
              fA6=pk(qa6.x,qa6.y), fA7=pk(qa7.x,qa7.y), fA8=pk(qa8.x,qa8.y);
    const u32 fB0=pk(qb0.x,qb0.y), fB1=pk(qb1.x,qb1.y), fB2=pk(qb2.x,qb2.y),
              fB3=pk(qb3.x,qb3.y), fB4=pk(qb4.x,qb4.y), fB5=pk(qb5.x,qb5.y),
              fB6=pk(qb6.x,qb6.y), fB7=pk(qb7.x,qb7.y), fB8=pk(qb8.x,qb8.y);

    // ---- e1 = relu(ef @ We1 + be1): 8 ch/lane, 9 k-pairs ----
    float4 eAa = ld4s(&sbe1[8*p]), eAb = ld4s(&sbe1[8*p+4]);
    float4 eBa = eAa, eBb = eAb;
    #define E1S(KP, AA, BB) { \
      const uint4 w0 = *(const uint4*)&sW[PW_WE1 + (KP)*E1DIM + 8*p]; \
      const uint4 w1 = *(const uint4*)&sW[PW_WE1 + (KP)*E1DIM + 8*p + 4]; \
      D4(eAa, w0, AA) D4(eAb, w1, AA) D4(eBa, w0, BB) D4(eBb, w1, BB) }
    E1S(0,fA0,fB0) E1S(1,fA1,fB1) E1S(2,fA2,fB2) E1S(3,fA3,fB3) E1S(4,fA4,fB4)
    E1S(5,fA5,fB5) E1S(6,fA6,fB6) E1S(7,fA7,fB7) E1S(8,fA8,fB8)
    #undef E1S
    relu4(eAa); relu4(eAb); relu4(eBa); relu4(eBb);
    {
      uint2 t0; t0.x = pk(eAa.x,eAa.y); t0.y = pk(eBa.x,eBa.y);
      uint2 t1; t1.x = pk(eAa.z,eAa.w); t1.y = pk(eBa.z,eBa.w);
      uint2 t2; t2.x = pk(eAb.x,eAb.y); t2.y = pk(eBb.x,eBb.y);
      uint2 t3; t3.x = pk(eAb.z,eAb.w); t3.y = pk(eBb.z,eBb.w);
      *(uint2*)&tb_[8*p+0] = t0; *(uint2*)&tb_[8*p+2] = t1;
      *(uint2*)&tb_[8*p+4] = t2; *(uint2*)&tb_[8*p+6] = t3;
    }
    // wave-lockstep + in-order DS pipe: team reads below see all 4 lanes' writes

    // ---- pe = relu(e1 @ We2 + be2) ----
    float4 pAa = ld4s(&sbe2[8*p]), pAb = ld4s(&sbe2[8*p+4]);
    float4 pBa = pAa, pBb = pAb;
    #pragma unroll 4
    for (int kp = 0; kp < 16; ++kp) {
      const uint2 ab = *(const uint2*)&tb_[2*kp];
      const uint4 w0 = *(const uint4*)&sW[PW_WE2 + kp*PEDIM + 8*p];
      const uint4 w1 = *(const uint4*)&sW[PW_WE2 + kp*PEDIM + 8*p + 4];
      D4(pAa, w0, ab.x) D4(pAb, w1, ab.x) D4(pBa, w0, ab.y) D4(pBb, w1, ab.y)
    }
    relu4(pAa); relu4(pAb); relu4(pBa); relu4(pBb);
    {
      uint2 t0; t0.x = pk(pAa.x,pAa.y); t0.y = pk(pBa.x,pBa.y);
      uint2 t1; t1.x = pk(pAa.z,pAa.w); t1.y = pk(pBa.z,pBa.w);
      uint2 t2; t2.x = pk(pAb.x,pAb.y); t2.y = pk(pBb.x,pBb.y);
      uint2 t3; t3.x = pk(pAb.z,pAb.w); t3.y = pk(pBb.z,pBb.w);
      *(uint2*)&tb_[8*p+0] = t0; *(uint2*)&tb_[8*p+2] = t1;
      *(uint2*)&tb_[8*p+4] = t2; *(uint2*)&tb_[8*p+6] = t3;
    }

    // ---- h (8 ch/lane) and g (16 ch/lane) from the pe broadcast ----
    float4 hAa = ld4s(&sba1[8*p]), hAb = ld4s(&sba1[8*p+4]);
    float4 hBa = hAa, hBb = hAb;
    float4 gA0 = ld4s(&sbg1[16*p]),   gA1 = ld4s(&sbg1[16*p+4]),
           gA2 = ld4s(&sbg1[16*p+8]), gA3 = ld4s(&sbg1[16*p+12]);
    float4 gB0 = gA0, gB1 = gA1, gB2 = gA2, gB3 = gA3;
    #pragma unroll 4
    for (int kp = 0; kp < 16; ++kp) {
      const uint2 ab = *(const uint2*)&tb_[2*kp];
      const uint4 wh0 = *(const uint4*)&sW[PW_WAE + kp*ADIM + 8*p];
      const uint4 wh1 = *(const uint4*)&sW[PW_WAE + kp*ADIM + 8*p + 4];
      D4(hAa, wh0, ab.x) D4(hAb, wh1, ab.x) D4(hBa, wh0, ab.y) D4(hBb, wh1, ab.y)
      const uint4 wg0 = *(const uint4*)&sW[PW_WGE + kp*GDIM + 16*p];
      const uint4 wg1 = *(const uint4*)&sW[PW_WGE + kp*GDIM + 16*p + 4];
      const uint4 wg2 = *(const uint4*)&sW[PW_WGE + kp*GDIM + 16*p + 8];
      const uint4 wg3 = *(const uint4*)&sW[PW_WGE + kp*GDIM + 16*p + 12];
      D4(gA0, wg0, ab.x) D4(gA1, wg1, ab.x) D4(gA2, wg2, ab.x) D4(gA3, wg3, ab.x)
      D4(gB0, wg0, ab.y) D4(gB1, wg1, ab.y) D4(gB2, wg2, ab.y) D4(gB3, wg3, ab.y)
    }
    // node-table adds (fp32)
    {
      const float* xjpA = wxaj + (size_t)jgA*ADIM + 8*p;
      const float* xjpB = wxaj + (size_t)jgB*ADIM + 8*p;
      add4(hAa, ld4s(xjpA)); add4(hAb, ld4s(xjpA + 4));
      add4(hBa, ld4s(xjpB)); add4(hBb, ld4s(xjpB + 4));
      add4(hAa, xai0); add4(hAb, xai1); add4(hBa, xai0); add4(hBb, xai1);
      const float* xgpA = wxg + (size_t)jgA*GDIM + 16*p;
      const float* xgpB = wxg + (size_t)jgB*GDIM + 16*p;
      add4(gA0, ld4s(xgpA)); add4(gA1, ld4s(xgpA+4)); add4(gA2, ld4s(xgpA+8)); add4(gA3, ld4s(xgpA+12));
      add4(gB0, ld4s(xgpB)); add4(gB1, ld4s(xgpB+4)); add4(gB2, ld4s(xgpB+8)); add4(gB3, ld4s(xgpB+12));
    }

    // ---- logits: team-reduce relu(h) @ Wa2 (fp32) ----
    const float4 wa20 = ld4s(&sWa2[8*p]), wa21 = ld4s(&sWa2[8*p+4]);
    float lpA = fmaxf(hAa.x,0.f)*wa20.x + fmaxf(hAa.y,0.f)*wa20.y
              + fmaxf(hAa.z,0.f)*wa20.z + fmaxf(hAa.w,0.f)*wa20.w
              + fmaxf(hAb.x,0.f)*wa21.x + fmaxf(hAb.y,0.f)*wa21.y
              + fmaxf(hAb.z,0.f)*wa21.z + fmaxf(hAb.w,0.f)*wa21.w;
    float lpB = fmaxf(hBa.x,0.f)*wa20.x + fmaxf(hBa.y,0.f)*wa20.y
              + fmaxf(hBa.z,0.f)*wa20.z + fmaxf(hBa.w,0.f)*wa20.w
              + fmaxf(hBb.x,0.f)*wa21.x + fmaxf(hBb.y,0.f)*wa21.y
              + fmaxf(hBb.z,0.f)*wa21.z + fmaxf(hBb.w,0.f)*wa21.w;
    lpA += __shfl_xor(lpA, 1); lpA += __shfl_xor(lpA, 2);
    lpB += __shfl_xor(lpB, 1); lpB += __shfl_xor(lpB, 2);
    const float lA = vA ? (lpA + ba2v) : -INFINITY;
    const float lB = vB ? (lpB + ba2v) : -INFINITY;

    // ---- online softmax over both edges ----
    const float mn1 = fmaxf(m, lA);
    const float al1 = (m  > -INFINITY) ? __expf(m  - mn1) : 0.f;
    const float w1  = (lA > -INFINITY) ? __expf(lA - mn1) : 0.f;
    const float s1  = s*al1 + w1;
    const float mn2 = fmaxf(mn1, lB);
    const float al2 = (mn1 > -INFINITY) ? __expf(mn1 - mn2) : 0.f;
    const float w2  = (lB  > -INFINITY) ? __expf(lB  - mn2) : 0.f;
    s = s1*al2 + w2;  m = mn2;
    const float aall = al1*al2, cA = w1*al2, cB = w2;

    // ---- stage relu(g) as f16 pairs (64 u32/team; TROW=68 accommodates) ----
    relu4(gA0); relu4(gA1); relu4(gA2); relu4(gA3);
    relu4(gB0); relu4(gB1); relu4(gB2); relu4(gB3);
    {
      uint2 t;
      t.x = pk(gA0.x,gA0.y); t.y = pk(gB0.x,gB0.y); *(uint2*)&tb_[16*p+0]  = t;
      t.x = pk(gA0.z,gA0.w); t.y = pk(gB0.z,gB0.w); *(uint2*)&tb_[16*p+2]  = t;
      t.x = pk(gA1.x,gA1.y); t.y = pk(gB1.x,gB1.y); *(uint2*)&tb_[16*p+4]  = t;
      t.x = pk(gA1.z,gA1.w); t.y = pk(gB1.z,gB1.w); *(uint2*)&tb_[16*p+6]  = t;
      t.x = pk(gA2.x,gA2.y); t.y = pk(gB2.x,gB2.y); *(uint2*)&tb_[16*p+8]  = t;
      t.x = pk(gA2.z,gA2.w); t.y = pk(gB2.z,gB2.w); *(uint2*)&tb_[16*p+10] = t;
      t.x = pk(gA3.x,gA3.y); t.y = pk(gB3.x,gB3.y); *(uint2*)&tb_[16*p+12] = t;
      t.x = pk(gA3.z,gA3.w); t.y = pk(gB3.z,gB3.w); *(uint2*)&tb_[16*p+14] = t;
    }

    // ---- gates matvec (64x64); Wg2 read from global (L1-hot broadcast) ----
    float4 aA0 = ld4s(&sbg2[16*p]),   aA1 = ld4s(&sbg2[16*p+4]),
           aA2 = ld4s(&sbg2[16*p+8]), aA3 = ld4s(&sbg2[16*p+12]);
    float4 aB0 = aA0, aB1 = aA1, aB2 = aA2, aB3 = aA3;
    #pragma unroll 4
    for (int kp = 0; kp < 32; ++kp) {
      const uint2 gg = *(const uint2*)&tb_[2*kp];
      const uint4 w0 = *(const uint4*)&pwWg2[kp*ODIM + 16*p];
      const uint4 w1 = *(const uint4*)&pwWg2[kp*ODIM + 16*p + 4];
      const uint4 w2 = *(const uint4*)&pwWg2[kp*ODIM + 16*p + 8];
      const uint4 w3 = *(const uint4*)&pwWg2[kp*ODIM + 16*p + 12];
      D4(aA0, w0, gg.x) D4(aA1, w1, gg.x) D4(aA2, w2, gg.x) D4(aA3, w3, gg.x)
      D4(aB0, w0, gg.y) D4(aB1, w1, gg.y) D4(aB2, w2, gg.y) D4(aB3, w3, gg.y)
    }

    // ---- acc = acc*aall + cA*sigmoid(gaA)*nei[jA] + cB*sigmoid(gaB)*nei[jB] ----
    const float* njpA = wnei + (size_t)jgA*ODIM + 16*p;
    const float* njpB = wnei + (size_t)jgB*ODIM + 16*p;
    const float4 nA0 = ld4s(njpA), nA1 = ld4s(njpA+4), nA2 = ld4s(njpA+8), nA3 = ld4s(njpA+12);
    const float4 nB0 = ld4s(njpB), nB1 = ld4s(njpB+4), nB2 = ld4s(njpB+8), nB3 = ld4s(njpB+12);
    #define ACCU(AC, GA, NA, GB, NB) \
      AC.x = AC.x*aall + cA*sigm((GA).x)*(NA).x + cB*sigm((GB).x)*(NB).x; \
      AC.y = AC.y*aall + cA*sigm((GA).y)*(NA).y + cB*sigm((GB).y)*(NB).y; \
      AC.z = AC.z*aall + cA*sigm((GA).z)*(NA).z + cB*sigm((GB).z)*(NB).z; \
      AC.w = AC.w*aall + cA*sigm((GA).w)*(NA).w + cB*sigm((GB).w)*(NB).w;
    ACCU(acc0, aA0, nA0, aB0, nB0)
    ACCU(acc1, aA1, nA1, aB1, nB1)
    ACCU(acc2, aA2, nA2, aB2, nB2)
    ACCU(acc3, aA3, nA3, aB3, nB3)
    #undef ACCU
  }

  // ---- per-wave merge across the 16 edge slots ----
  const float mw = wredmax(m);
  const float alphaF = (s > 0.f) ? __expf(m - mw) : 0.f;
  const float sl = wredsum(s * alphaF);
  acc0.x = wredsum(acc0.x * alphaF); acc0.y = wredsum(acc0.y * alphaF);
  acc0.z = wredsum(acc0.z * alphaF); acc0.w = wredsum(acc0.w * alphaF);
  acc1.x = wredsum(acc1.x * alphaF); acc1.y = wredsum(acc1.y * alphaF);
  acc1.z = wredsum(acc1.z * alphaF); acc1.w = wredsum(acc1.w * alphaF);
  acc2.x = wredsum(acc2.x * alphaF); acc2.y = wredsum(acc2.y * alphaF);
  acc2.z = wredsum(acc2.z * alphaF); acc2.w = wredsum(acc2.w * alphaF);
  acc3.x = wredsum(acc3.x * alphaF); acc3.y = wredsum(acc3.y * alphaF);
  acc3.z = wredsum(acc3.z * alphaF); acc3.w = wredsum(acc3.w * alphaF);
  if (e == 0) {
    if (p == 0) { smerge[wv][0] = mw; smerge[wv][1] = sl; }
    *(float4*)&smerge[wv][8 + 16*p + 0]  = acc0;
    *(float4*)&smerge[wv][8 + 16*p + 4]  = acc1;
    *(float4*)&smerge[wv][8 + 16*p + 8]  = acc2;
    *(float4*)&smerge[wv][8 + 16*p + 12] = acc3;
  }
  __syncthreads();

  // ---- cross-wave merge + write msg (wave 0) ----
  if (tid < ODIM) {
    const float mw0 = smerge[0][0], sl0 = smerge[0][1];
    const float mw1 = smerge[1][0], sl1 = smerge[1][1];
    const float MW = fmaxf(mw0, mw1);
    const float b0 = (sl0 > 0.f) ? __expf(mw0 - MW) : 0.f;
    const float b1 = (sl1 > 0.f) ? __expf(mw1 - MW) : 0.f;
    const float denom = sl0*b0 + sl1*b1;
    const float rs = 1.f / fmaxf(denom, 1e-30f);
    ws[OFF_MSG + (size_t)row*ODIM + tid] =
        (smerge[0][8+tid]*b0 + smerge[1][8+tid]*b1) * rs;
  }
}

// ---------------- Kernel C: output MLP (fp32) ----------------
__global__ __launch_bounds__(64) void final_out(
    const float* __restrict__ ws, const float* __restrict__ Wc1, const float* __restrict__ bc1,
    const float* __restrict__ Wc2, const float* __restrict__ bc2, float* __restrict__ out)
{
  const int n = blockIdx.x, o = threadIdx.x;
  __shared__ float comb[2*ODIM];
  __shared__ float h1[ODIM];
  comb[o] = ws[OFF_SELF + n*ODIM + o];
  comb[ODIM + o] = ws[OFF_MSG + n*ODIM + o];
  __syncthreads();
  float a = bc1[o];
  #pragma unroll
  for (int t = 0; t < 2*ODIM; ++t) a += comb[t] * Wc1[t*ODIM + o];
  h1[o] = fmaxf(a, 0.f);
  __syncthreads();
  float b = bc2[o];
  #pragma unroll
  for (int t = 0; t < ODIM; ++t) b += h1[t] * Wc2[t*ODIM + o];
  out[n*ODIM + o] = b;
}

extern "C" void kernel_launch(void* const* d_in, const int* in_sizes, int n_in,
                              void* d_out, int out_size, void* d_ws, size_t ws_size,
                              hipStream_t stream)
{
  const float* x   = (const float*)d_in[0];
  const float* adj = (const float*)d_in[1];
  const float* ef  = (const float*)d_in[2];
  const float* Ws  = (const float*)d_in[3];
  const float* bs  = (const float*)d_in[4];
  const float* Wn  = (const float*)d_in[5];
  const float* bn  = (const float*)d_in[6];
  const float* We1 = (const float*)d_in[7];
  const float* be1 = (const float*)d_in[8];
  const float* We2 = (const float*)d_in[9];
  const float* be2 = (const float*)d_in[10];
  const float* Wa1 = (const float*)d_in[11];
  const float* ba1 = (const float*)d_in[12];
  const float* Wa2 = (const float*)d_in[13];
  const float* ba2 = (const float*)d_in[14];
  const float* Wg1 = (const float*)d_in[15];
  const float* bg1 = (const float*)d_in[16];
  const float* Wg2 = (const float*)d_in[17];
  const float* bg2 = (const float*)d_in[18];
  const float* Wc1 = (const float*)d_in[19];
  const float* bc1 = (const float*)d_in[20];
  const float* Wc2 = (const float*)d_in[21];
  const float* bc2 = (const float*)d_in[22];
  float* ws  = (float*)d_ws;
  u32* pw = (u32*)(ws + OFF_PKW);
  float* out = (float*)d_out;

  pack_weights<<<(PW_TOT + 255)/256, 256, 0, stream>>>(We1, We2, Wa1, Wg1, Wg2, pw);
  node_pre<<<NROWS, 64, 0, stream>>>(x, Ws, bs, Wn, bn, Wa1, Wg1, ws);
  edge_rows<<<NROWS, 128, 0, stream>>>(adj, ef, be1, be2, ba1, Wa2, ba2, bg1, bg2,
                                       pw, ws);
  final_out<<<NROWS, 64, 0, stream>>>(ws, Wc1, bc1, Wc2, bc2, out);
}